// Round 8
// baseline (207.149 us; speedup 1.0000x reference)
//
#include <hip/hip_runtime.h>
#include <math.h>

#define BB  64
#define WW  128
#define NN  64
#define HIDN 77
#define NBLK 256

// -------- device-scope grid barrier (all NBLK blocks guaranteed resident) --------
__device__ __forceinline__ void gbar(int* cnt, int target) {
  __syncthreads();
  if (threadIdx.x == 0) {
    __threadfence();                 // release my block's prior global writes
    atomicAdd(cnt, 1);               // device-scope by default on gfx950
    while (atomicAdd(cnt, 0) < target) __builtin_amdgcn_s_sleep(16);
    __threadfence();                 // acquire other blocks' writes
  }
  __syncthreads();
}

// ================= mega-kernel: all phases, 5 grid barriers =================
__global__ __launch_bounds__(512, 2) void k_all(
    const float* __restrict__ x, const float* __restrict__ emb,
    const float* __restrict__ wg, const float* __restrict__ gcn_b,
    const float* __restrict__ w1, const float* __restrict__ b1,
    const float* __restrict__ w2, const float* __restrict__ b2,
    const float* __restrict__ ta_w, const float* __restrict__ ta_b,
    const float* __restrict__ ta_a, const float* __restrict__ ta_bias,
    const float* __restrict__ gat_w, const float* __restrict__ gat_asrc,
    const float* __restrict__ gat_adst, const float* __restrict__ gat_b,
    const float* __restrict__ fcw, const float* __restrict__ fcb,
    const int* __restrict__ gat_ei, int E_gat,
    const int* __restrict__ gl_ei, int E_gl,
    float* XW, float* XS, float* LEFT, float* RIGHT, float* HT, float* H2,
    float* SSRC, float* SDST, int* GATOFF, int* GATLIST, int* BCNT,
    float* out_rec, float* out_pre) {
  __shared__ float smem[20176];   // 80704 B arena, aliased per phase
  int tid = threadIdx.x;
  int bid = blockIdx.x;

  // ---------------- P1: XW = [x^T | emb] @ gcn_w ----------------
  {
    float* Ws = smem;               // 140*128 = 17920 f
    float* As = smem + 17920;       // 16*141 = 2256 f
    int r0 = bid * 16;
    int b = r0 >> 6, n0 = r0 & 63;
    const float4* W4 = (const float4*)wg;
    float4* Ws4 = (float4*)Ws;
    for (int t = tid; t < 4480; t += 512) Ws4[t] = W4[t];
    const float* xb = x + (size_t)b * 8192 + n0;
    for (int t = tid; t < 2048; t += 512) {
      int w = t >> 4, i = t & 15;
      As[i * 141 + w] = xb[w * 64 + i];
    }
    if (tid < 192) {
      int i = tid / 12, j = tid % 12;
      As[i * 141 + 128 + j] = emb[(n0 + i) * 12 + j];
    }
    __syncthreads();
    if (tid < 256) {
      int tx = tid & 31, ty = tid >> 5;
      int row0 = ty * 2;
      float a00 = 0, a01 = 0, a02 = 0, a03 = 0, a10 = 0, a11 = 0, a12 = 0, a13 = 0;
      const float* A0 = As + row0 * 141;
      const float* A1 = A0 + 141;
#pragma unroll 4
      for (int k = 0; k < 140; k++) {
        float4 wv = *(const float4*)&Ws[k * 128 + tx * 4];
        float a0 = A0[k], a1 = A1[k];
        a00 += a0 * wv.x; a01 += a0 * wv.y; a02 += a0 * wv.z; a03 += a0 * wv.w;
        a10 += a1 * wv.x; a11 += a1 * wv.y; a12 += a1 * wv.z; a13 += a1 * wv.w;
      }
      float* o = XW + (size_t)(r0 + row0) * 128 + tx * 4;
      *(float4*)o = make_float4(a00, a01, a02, a03);
      *(float4*)(o + 128) = make_float4(a10, a11, a12, a13);
    }
    // block 1: build GAT CSR (uses As region after compute done)
    if (bid == 1) {
      __syncthreads();
      int* ip   = (int*)As;
      int* offs = ip;          // 65
      int* cur  = ip + 65;     // 64
      int* cntg = ip + 129;    // 64
      int* lst  = ip + 193;    // up to 1344 (<= 2256-193)
      if (tid < 64) cntg[tid] = 1;
      __syncthreads();
      for (int e = tid; e < E_gat; e += 512) atomicAdd(&cntg[gat_ei[BB * E_gat + e]], 1);
      __syncthreads();
      if (tid == 0) { int s = 0; for (int n = 0; n < 64; n++) { offs[n] = s; s += cntg[n]; } offs[64] = s; }
      __syncthreads();
      if (tid < 64) cur[tid] = offs[tid];
      __syncthreads();
      for (int e = tid; e < E_gat; e += 512) {
        int src = gat_ei[e], dst = gat_ei[BB * E_gat + e];
        lst[atomicAdd(&cur[dst], 1)] = src;
      }
      if (tid < 64) lst[atomicAdd(&cur[tid], 1)] = tid;
      __syncthreads();
      if (tid < 65) GATOFF[tid] = offs[tid];
      int tot = offs[64];
      for (int t = tid; t < tot; t += 512) GATLIST[t] = lst[t];
    }
  }
  gbar(BCNT, NBLK);

  // ---------------- P2+P3: sagg (hA in LDS) + MLP -> XS, out_rec ----------------
  {
    float* As1  = smem;             // 16*132 = 2112 f
    float* hm   = smem + 2112;      // 16*80  = 1280 f
    float* xbt  = smem + 3392;      // 16*132 = 2112 f
    float* recT = smem + 5504;      // 128*17 = 2176 f
    float* XWb  = smem + 7680;      // 64*132 = 8448 f
    float* Sm   = smem + 16128;     // 16*68  = 1088 f
    float* gbb  = smem + 17216;     // 128
    float* dinv = smem + 17344;     // 64
    int*   cnt  = (int*)(smem + 17408); // 64
    float* Wbuf = smem + 7680;      // 10240 f (aliases XWb..cnt after P2 compute)

    int r0 = bid * 16;
    int b = r0 >> 6, n0 = r0 & 63;
    const float* xb = x + (size_t)b * 8192 + n0;

    // stage XW[b] full, build S rows, stage xbt
    {
      const float4* xw4 = (const float4*)(XW + (size_t)b * 8192);
      for (int t = tid; t < 2048; t += 512) {
        int row = t >> 5, c4 = t & 31;
        *(float4*)&XWb[row * 132 + c4 * 4] = xw4[t];
      }
    }
    for (int t = tid; t < 1088; t += 512) Sm[t] = 0.f;
    for (int t = tid; t < 2048; t += 512) {
      int w = t >> 4, i = t & 15;
      xbt[i * 132 + w] = xb[w * 64 + i];
    }
    if (tid < 128) gbb[tid] = gcn_b[tid];
    if (tid < 64) cnt[tid] = 1;
    __syncthreads();
    for (int e = tid; e < E_gl; e += 512) {
      int dst = gl_ei[BB * E_gl + e];
      atomicAdd(&cnt[dst], 1);
      int d = dst - n0;
      if ((unsigned)d < 16u) Sm[d * 68 + gl_ei[e]] = 1.0f;
    }
    __syncthreads();
    if (tid < 64) dinv[tid] = rsqrtf((float)cnt[tid]);
    __syncthreads();
    for (int t = tid; t < 1088; t += 512) {
      int i = t / 68, s = t % 68;
      if (s < 64) {
        float di = dinv[n0 + i];
        float v = Sm[t] * dinv[s] * di;
        if (s == n0 + i) v += di * di;
        Sm[t] = v;
      }
    }
    __syncthreads();
    // P2 compute: As1 = relu(S @ XWb + b)
    if (tid < 256) {
      int tx = tid & 31, ty = tid >> 5;
      int row0 = ty * 2, c0 = tx * 4;
      float a00 = 0, a01 = 0, a02 = 0, a03 = 0, a10 = 0, a11 = 0, a12 = 0, a13 = 0;
      const float* S0 = Sm + row0 * 68;
      const float* S1 = S0 + 68;
#pragma unroll 4
      for (int s = 0; s < 64; s++) {
        float4 wv = *(const float4*)&XWb[s * 132 + c0];
        float a0 = S0[s], a1 = S1[s];
        a00 += a0 * wv.x; a01 += a0 * wv.y; a02 += a0 * wv.z; a03 += a0 * wv.w;
        a10 += a1 * wv.x; a11 += a1 * wv.y; a12 += a1 * wv.z; a13 += a1 * wv.w;
      }
      float4 bv = *(const float4*)&gbb[c0];
      *(float4*)&As1[row0 * 132 + c0] = make_float4(
          fmaxf(a00 + bv.x, 0.f), fmaxf(a01 + bv.y, 0.f),
          fmaxf(a02 + bv.z, 0.f), fmaxf(a03 + bv.w, 0.f));
      *(float4*)&As1[(row0 + 1) * 132 + c0] = make_float4(
          fmaxf(a10 + bv.x, 0.f), fmaxf(a11 + bv.y, 0.f),
          fmaxf(a12 + bv.z, 0.f), fmaxf(a13 + bv.w, 0.f));
    }
    __syncthreads();
    // stage W1 (over XWb region)
    for (int t = tid; t < 10240; t += 512) {
      int k = t / 80, c = t % 80;
      Wbuf[t] = (c < HIDN) ? w1[k * HIDN + c] : 0.f;
    }
    __syncthreads();
    // MLP phase 1: hm = tanh(As1 @ W1 + b1)
    if (tid < 256) {
      int tx = tid & 31, ty = tid >> 5;
      int row0 = ty * 2, c0 = tx * 4;
      bool act = c0 < HIDN;
      int cW = act ? c0 : 0;
      float a00 = 0, a01 = 0, a02 = 0, a03 = 0, a10 = 0, a11 = 0, a12 = 0, a13 = 0;
      const float* A0 = As1 + row0 * 132;
      const float* A1 = A0 + 132;
#pragma unroll 4
      for (int k = 0; k < 128; k++) {
        float4 wv = *(const float4*)&Wbuf[k * 80 + cW];
        float a0 = A0[k], a1 = A1[k];
        a00 += a0 * wv.x; a01 += a0 * wv.y; a02 += a0 * wv.z; a03 += a0 * wv.w;
        a10 += a1 * wv.x; a11 += a1 * wv.y; a12 += a1 * wv.z; a13 += a1 * wv.w;
      }
      if (act) {
        float r0v[4] = {a00, a01, a02, a03}, r1v[4] = {a10, a11, a12, a13};
#pragma unroll
        for (int j = 0; j < 4; j++) {
          if (c0 + j < HIDN) {
            float bb = b1[c0 + j];
            hm[row0 * 80 + c0 + j] = tanhf(r0v[j] + bb);
            hm[(row0 + 1) * 80 + c0 + j] = tanhf(r1v[j] + bb);
          }
        }
      }
    }
    __syncthreads();
    // stage W2
    {
      const float4* w24 = (const float4*)w2;
      float4* Wb4 = (float4*)Wbuf;
      for (int t = tid; t < 2464; t += 512) Wb4[t] = w24[t];
    }
    __syncthreads();
    // MLP phase 2: x_rec, xs, recT
    if (tid < 256) {
      int tx = tid & 31, ty = tid >> 5;
      int row0 = ty * 2, c0 = tx * 4;
      float a00 = 0, a01 = 0, a02 = 0, a03 = 0, a10 = 0, a11 = 0, a12 = 0, a13 = 0;
      const float* H0 = hm + row0 * 80;
      const float* H1 = H0 + 80;
#pragma unroll 4
      for (int k = 0; k < HIDN; k++) {
        float4 wv = *(const float4*)&Wbuf[k * 128 + c0];
        float a0 = H0[k], a1 = H1[k];
        a00 += a0 * wv.x; a01 += a0 * wv.y; a02 += a0 * wv.z; a03 += a0 * wv.w;
        a10 += a1 * wv.x; a11 += a1 * wv.y; a12 += a1 * wv.z; a13 += a1 * wv.w;
      }
      float4 bv = *(const float4*)&b2[c0];
      float x00 = tanhf(a00 + bv.x), x01 = tanhf(a01 + bv.y), x02 = tanhf(a02 + bv.z), x03 = tanhf(a03 + bv.w);
      float x10 = tanhf(a10 + bv.x), x11 = tanhf(a11 + bv.y), x12 = tanhf(a12 + bv.z), x13 = tanhf(a13 + bv.w);
      const float* X0 = xbt + row0 * 132;
      const float* X1 = X0 + 132;
      *(float4*)&XS[(size_t)(r0 + row0) * 128 + c0] =
          make_float4(X0[c0] + x00, X0[c0 + 1] + x01, X0[c0 + 2] + x02, X0[c0 + 3] + x03);
      *(float4*)&XS[(size_t)(r0 + row0 + 1) * 128 + c0] =
          make_float4(X1[c0] + x10, X1[c0 + 1] + x11, X1[c0 + 2] + x12, X1[c0 + 3] + x13);
      recT[(c0 + 0) * 17 + row0] = x00; recT[(c0 + 1) * 17 + row0] = x01;
      recT[(c0 + 2) * 17 + row0] = x02; recT[(c0 + 3) * 17 + row0] = x03;
      recT[(c0 + 0) * 17 + row0 + 1] = x10; recT[(c0 + 1) * 17 + row0 + 1] = x11;
      recT[(c0 + 2) * 17 + row0 + 1] = x12; recT[(c0 + 3) * 17 + row0 + 1] = x13;
    }
    __syncthreads();
    float* orc = out_rec + (size_t)b * 8192 + n0;
    for (int t = tid; t < 2048; t += 512) {
      int w = t >> 4, i = t & 15;
      orc[w * 64 + i] = recT[w * 17 + i];
    }
  }
  gbar(BCNT, 2 * NBLK);

  // ---------------- P4: left/right projections ----------------
  {
    int wave = tid >> 6, lane = tid & 63;
    int gw = bid * 8 + wave;           // 0..2047
    int c = lane * 2;
#pragma unroll
    for (int rep = 0; rep < 4; rep++) {
      int idx = gw + rep * 2048;       // 0..8191
      int b = idx >> 7, e = idx & 127;
      const float* xsb = XS + (size_t)b * 8192;
      float lx = 0, ly = 0, rx = 0, ry = 0;
#pragma unroll 4
      for (int n = 0; n < 64; n++) {
        float wl = ta_w[n * 128 + e];
        float wr = ta_w[(64 + n) * 128 + e];
        float2 xv = *(const float2*)&xsb[n * 128 + c];
        lx += wl * xv.x; ly += wl * xv.y;
        rx += wr * xv.x; ry += wr * xv.y;
      }
      float tb = ta_b[e];
      *(float2*)&LEFT[((size_t)b * 128 + e) * 128 + c] = make_float2(lx + tb, ly + tb);
      *(float2*)&RIGHT[((size_t)b * 128 + e) * 128 + c] = make_float2(rx, ry);
    }
  }
  gbar(BCNT, 3 * NBLK);

  // ---------------- P5: attn (R read from L1/L2, no R staging) ----------------
  {
    float* Lh  = smem;              // [128][32] then P[32][132]; 4224 f
    float* xsT = smem + 4224;       // 128*68 = 8704 f
    float* av2 = smem + 12928;      // 128
    float* av6 = smem + 13056;      // 128
    float* uu  = smem + 13184;      // 32
    float* vv  = smem + 13216;      // 128
    int b = bid >> 2, q = bid & 3;
    int i0 = q * 32;
    const float* Rg = RIGHT + (size_t)b * 16384;
    {
      const float* Lp = LEFT + (size_t)b * 16384 + i0;
      for (int t = tid; t < 4096; t += 512)
        Lh[t] = Lp[(t >> 5) * 128 + (t & 31)];
    }
    {
      const float* xsb = XS + (size_t)b * 8192;
      for (int t = tid; t < 8192; t += 512)
        xsT[(t & 127) * 68 + (t >> 7)] = xsb[t];
    }
    if (tid < 128) { float a = ta_a[tid]; av2[tid] = 0.4f * a; av6[tid] = 0.6f * a; }
    __syncthreads();
    if (tid < 160) {
      float acc = 0.f;
      if (tid < 128) {
        for (int e = 0; e < 128; e++) acc += av6[e] * Rg[e * 128 + tid];
        vv[tid] = acc;
      } else {
        int i = tid - 128;
        for (int e = 0; e < 128; e++) acc += av6[e] * Lh[e * 32 + i];
        uu[i] = acc;
      }
    }
    __syncthreads();

    int tj = tid & 31, ti = tid >> 5;
    float acc[2][4];
#pragma unroll
    for (int a = 0; a < 2; a++)
#pragma unroll
      for (int j = 0; j < 4; j++) acc[a][j] = 0.f;
#pragma unroll 2
    for (int e = 0; e < 128; e++) {
      float2 L = *(const float2*)&Lh[e * 32 + ti * 2];
      float4 R = *(const float4*)&Rg[e * 128 + tj * 4];
      float ae = av2[e];
      float Ra[4] = {R.x, R.y, R.z, R.w};
      float La[2] = {L.x, L.y};
#pragma unroll
      for (int a = 0; a < 2; a++)
#pragma unroll
        for (int j = 0; j < 4; j++) {
          float t = La[a] + Ra[j];
          acc[a][j] += ae * fabsf(t);
        }
    }
    float p[2][4];
#pragma unroll
    for (int a = 0; a < 2; a++) {
      int i = i0 + ti * 2 + a;
      float uvi = uu[ti * 2 + a];
      float4 bv = *(const float4*)&ta_bias[(size_t)i * 128 + tj * 4];
      float v0 = acc[a][0] + bv.x + uvi + vv[tj * 4 + 0];
      float v1 = acc[a][1] + bv.y + uvi + vv[tj * 4 + 1];
      float v2 = acc[a][2] + bv.z + uvi + vv[tj * 4 + 2];
      float v3 = acc[a][3] + bv.w + uvi + vv[tj * 4 + 3];
      float m = fmaxf(fmaxf(v0, v1), fmaxf(v2, v3));
#pragma unroll
      for (int o = 16; o > 0; o >>= 1) m = fmaxf(m, __shfl_xor(m, o));
      float e0 = __expf(v0 - m), e1 = __expf(v1 - m), e2 = __expf(v2 - m), e3 = __expf(v3 - m);
      float s = e0 + e1 + e2 + e3;
#pragma unroll
      for (int o = 16; o > 0; o >>= 1) s += __shfl_xor(s, o);
      float inv = 1.f / s;
      p[a][0] = e0 * inv; p[a][1] = e1 * inv; p[a][2] = e2 * inv; p[a][3] = e3 * inv;
    }
    __syncthreads();
    float* P = Lh;  // [32][132]
    *(float4*)&P[(ti * 2 + 0) * 132 + tj * 4] = make_float4(p[0][0], p[0][1], p[0][2], p[0][3]);
    *(float4*)&P[(ti * 2 + 1) * 132 + tj * 4] = make_float4(p[1][0], p[1][1], p[1][2], p[1][3]);
    __syncthreads();
    int tn = tid & 15, i2 = tid >> 4;
    float o0 = 0, o1 = 0, o2 = 0, o3 = 0;
    const float* Prow = P + i2 * 132;
#pragma unroll 4
    for (int j = 0; j < 128; j++) {
      float4 xv = *(const float4*)&xsT[j * 68 + tn * 4];
      float pv = Prow[j];
      o0 += pv * xv.x; o1 += pv * xv.y; o2 += pv * xv.z; o3 += pv * xv.w;
    }
    float* hto = HT + (size_t)b * 8192 + (size_t)(i0 + i2) * 64 + tn * 4;
    *(float4*)hto = make_float4(tanhf(o0), tanhf(o1), tanhf(o2), tanhf(o3));
  }
  gbar(BCNT, 4 * NBLK);

  // ---------------- P6: h2 = hg @ gat_w + ssrc/sdst ----------------
  {
    float* Ws = smem;               // 128*128 = 16384 f
    float* As = smem + 16384;       // 16*132 = 2112 f
    int r0 = bid * 16;
    int b = r0 >> 6, n0 = r0 & 63;
    {
      const float4* W4 = (const float4*)gat_w;
      float4* Ws4 = (float4*)Ws;
      for (int t = tid; t < 4096; t += 512) Ws4[t] = W4[t];
    }
    const float* hb = HT + (size_t)b * 8192 + n0;
    for (int t = tid; t < 2048; t += 512) {
      int k = t >> 4, i = t & 15;
      As[i * 132 + k] = hb[k * 64 + i];
    }
    __syncthreads();
    if (tid < 256) {
      int tx = tid & 31, ty = tid >> 5;
      int row0 = ty * 2, c0 = tx * 4;
      float a00 = 0, a01 = 0, a02 = 0, a03 = 0, a10 = 0, a11 = 0, a12 = 0, a13 = 0;
      const float* A0 = As + row0 * 132;
      const float* A1 = A0 + 132;
#pragma unroll 4
      for (int k = 0; k < 128; k++) {
        float4 wv = *(const float4*)&Ws[k * 128 + c0];
        float a0 = A0[k], a1 = A1[k];
        a00 += a0 * wv.x; a01 += a0 * wv.y; a02 += a0 * wv.z; a03 += a0 * wv.w;
        a10 += a1 * wv.x; a11 += a1 * wv.y; a12 += a1 * wv.z; a13 += a1 * wv.w;
      }
      float4 as4 = *(const float4*)&gat_asrc[c0];
      float4 ad4 = *(const float4*)&gat_adst[c0];
      float* o = H2 + (size_t)(r0 + row0) * 128 + c0;
      *(float4*)o = make_float4(a00, a01, a02, a03);
      *(float4*)(o + 128) = make_float4(a10, a11, a12, a13);
      float ss0 = a00 * as4.x + a01 * as4.y + a02 * as4.z + a03 * as4.w;
      float sd0 = a00 * ad4.x + a01 * ad4.y + a02 * ad4.z + a03 * ad4.w;
      float ss1 = a10 * as4.x + a11 * as4.y + a12 * as4.z + a13 * as4.w;
      float sd1 = a10 * ad4.x + a11 * ad4.y + a12 * ad4.z + a13 * ad4.w;
#pragma unroll
      for (int o2 = 16; o2 > 0; o2 >>= 1) {
        ss0 += __shfl_xor(ss0, o2); sd0 += __shfl_xor(sd0, o2);
        ss1 += __shfl_xor(ss1, o2); sd1 += __shfl_xor(sd1, o2);
      }
      if (tx == 0) {
        SSRC[r0 + row0] = ss0; SDST[r0 + row0] = sd0;
        SSRC[r0 + row0 + 1] = ss1; SDST[r0 + row0 + 1] = sd1;
      }
    }
  }
  gbar(BCNT, 5 * NBLK);

  // ---------------- P7: GAT edge-softmax aggregate + FC + tanh ----------------
  {
    int wave = tid >> 6, lane = tid & 63;
    int gw = bid * 8 + wave;       // 0..2047
    int c = lane * 2;
#pragma unroll
    for (int rep = 0; rep < 2; rep++) {
      int r = gw + rep * 2048;     // 0..4095
      int b = r >> 6, n = r & 63;
      int e0 = GATOFF[n], e1 = GATOFF[n + 1];
      int deg = e1 - e0, m = deg < 64 ? deg : 64;
      const float* sb = SSRC + b * 64;
      float sd = SDST[r];
      int el = 0; float evl = -1e30f;
      if (lane < m) {
        el = GATLIST[e0 + lane];
        float t = sb[el] + sd;
        evl = fmaxf(t, 0.2f * t);
      }
      float mx = evl;
#pragma unroll
      for (int o = 32; o > 0; o >>= 1) mx = fmaxf(mx, __shfl_xor(mx, o));
      for (int e = e0 + 64; e < e1; e++) {
        int s = GATLIST[e]; float t = sb[s] + sd; t = fmaxf(t, 0.2f * t);
        mx = fmaxf(mx, t);
      }
      float wl = (lane < m) ? __expf(evl - mx) : 0.f;
      float den = wl;
#pragma unroll
      for (int o = 32; o > 0; o >>= 1) den += __shfl_xor(den, o);
      const float* hb = H2 + (size_t)b * 8192;
      float ax = 0.f, ay = 0.f;
      for (int e = 0; e < m; e++) {
        int s = __shfl(el, e); float w = __shfl(wl, e);
        float2 h = *(const float2*)&hb[s * 128 + c];
        ax += w * h.x; ay += w * h.y;
      }
      for (int e = e0 + 64; e < e1; e++) {
        int s = GATLIST[e]; float t = sb[s] + sd; t = fmaxf(t, 0.2f * t);
        float w = __expf(t - mx);
        den += w;
        float2 h = *(const float2*)&hb[s * 128 + c];
        ax += w * h.x; ay += w * h.y;
      }
      float inv = 1.f / den;
      float o0 = ax * inv + gat_b[c], o1 = ay * inv + gat_b[c + 1];
      float xp = o0 * fcw[c] + o1 * fcw[c + 1];
#pragma unroll
      for (int o2 = 32; o2 > 0; o2 >>= 1) xp += __shfl_xor(xp, o2);
      if (lane == 0) out_pre[r] = tanhf(xp + fcb[0]);
    }
  }
}

extern "C" void kernel_launch(void* const* d_in, const int* in_sizes, int n_in,
                              void* d_out, int out_size, void* d_ws, size_t ws_size,
                              hipStream_t stream) {
  (void)n_in; (void)out_size; (void)ws_size;
  const float* x        = (const float*)d_in[0];
  const float* gl_embed = (const float*)d_in[7];
  const float* gcn_w    = (const float*)d_in[8];
  const float* gcn_b    = (const float*)d_in[9];
  const float* mlp_w1   = (const float*)d_in[10];
  const float* mlp_b1   = (const float*)d_in[11];
  const float* mlp_w2   = (const float*)d_in[12];
  const float* mlp_b2   = (const float*)d_in[13];
  const float* ta_w     = (const float*)d_in[14];
  const float* ta_b     = (const float*)d_in[15];
  const float* ta_a     = (const float*)d_in[16];
  const float* ta_bias  = (const float*)d_in[17];
  const float* gat_w    = (const float*)d_in[18];
  const float* gat_asrc = (const float*)d_in[19];
  const float* gat_adst = (const float*)d_in[20];
  const float* gat_b    = (const float*)d_in[21];
  const float* fc_w     = (const float*)d_in[22];
  const float* fc_b     = (const float*)d_in[23];
  const int*   gat_ei   = (const int*)d_in[24];
  const int*   gl_ei    = (const int*)d_in[25];

  int E_gat = in_sizes[24] / (2 * BB);  // 1280
  int E_gl  = in_sizes[25] / (2 * BB);  // 1638

  float* ws = (float*)d_ws;
  float* XW    = ws + 0;        // 524288
  float* XS    = ws + 524288;   // 524288
  float* LEFT  = ws + 1048576;  // 1048576
  float* RIGHT = ws + 2097152;  // 1048576
  float* HT    = ws + 3145728;  // 524288
  float* H2    = ws + 3670016;  // 524288
  float* SSRC  = ws + 4194304;  // 4096
  float* SDST  = ws + 4198400;  // 4096
  int*   IP    = (int*)(ws + 4202496);
  int* GATOFF  = IP;            // 72
  int* GATLIST = IP + 72;       // 2048
  int* BCNT    = IP + 2120;     // 1 (barrier counter)

  float* out_rec = (float*)d_out;
  float* out_pre = (float*)d_out + 524288;

  hipMemsetAsync(BCNT, 0, sizeof(int), stream);
  k_all<<<NBLK, 512, 0, stream>>>(x, gl_embed, gcn_w, gcn_b, mlp_w1, mlp_b1, mlp_w2, mlp_b2,
                                  ta_w, ta_b, ta_a, ta_bias, gat_w, gat_asrc, gat_adst, gat_b,
                                  fc_w, fc_b, gat_ei, E_gat, gl_ei, E_gl,
                                  XW, XS, LEFT, RIGHT, HT, H2, SSRC, SDST,
                                  GATOFF, GATLIST, BCNT, out_rec, out_pre);
}

// Round 9
// 113.752 us; speedup vs baseline: 1.8211x; 1.8211x over previous
//
#include <hip/hip_runtime.h>
#include <math.h>

#define BB  64
#define WW  128
#define NN  64
#define HIDN 77

// ================= K1: fused front: hA=(S@[x|emb])@W -> MLP -> xs, out_rec =================
// 256 blocks x 512 thr, 94.7 KB LDS (1 blk/CU, 8 waves). Block 1 tail-builds GAT CSR.
__global__ __launch_bounds__(512) void k_front(
    const float* __restrict__ x, const float* __restrict__ emb,
    const float* __restrict__ wg, const float* __restrict__ gcn_b,
    const float* __restrict__ w1, const float* __restrict__ b1,
    const float* __restrict__ w2, const float* __restrict__ b2,
    const int* __restrict__ gl_ei, int E_gl,
    const int* __restrict__ gat_ei, int E_gat,
    float* __restrict__ xs, float* __restrict__ out_rec,
    int* __restrict__ gat_off, int* __restrict__ gat_list) {
  __shared__ float smem[23680];            // 94720 B
  float* Ws   = smem;                      // 17920 (140x128)
  float* XA   = smem + 17920;              // 2304  (16x144): S@[x|emb], then hA
  float* Sm   = smem + 20224;              // 1088  (16x68)
  float* gbb  = smem + 21312;              // 128
  float* dinv = smem + 21440;              // 64
  int*   cnt  = (int*)(smem + 21504);      // 64
  float* xbt  = smem + 21568;              // 2112  (16x132)
  // aliases over Ws after GEMM1:
  float* Wbuf = smem;                      // 10240 (W1 [128][80] then W2 [77][128])
  float* hm   = smem + 10240;              // 1280  (16x80)
  float* recT = smem + 11520;              // 2176  (128x17)

  int tid = threadIdx.x;
  int r0 = blockIdx.x * 16;
  int b = r0 >> 6, n0 = r0 & 63;
  const float* xb  = x + (size_t)b * 8192;        // full batch slice
  const float* xb2 = xb + n0;                     // 16-row transposed tile base

  // P0: stage Ws, xbt; init Sm/cnt/gbb
  {
    const float4* W4 = (const float4*)wg;
    float4* Ws4 = (float4*)Ws;
    for (int t = tid; t < 4480; t += 512) Ws4[t] = W4[t];
  }
  for (int t = tid; t < 2048; t += 512) {
    int w = t >> 4, i = t & 15;
    xbt[i * 132 + w] = xb2[w * 64 + i];
  }
  for (int t = tid; t < 1088; t += 512) Sm[t] = 0.f;
  if (tid < 128) gbb[tid] = gcn_b[tid];
  if (tid < 64) cnt[tid] = 1;  // self-loop
  __syncthreads();

  // P1: edge scan: degree + indicator in owned S rows
  for (int e = tid; e < E_gl; e += 512) {
    int dst = gl_ei[BB * E_gl + e];
    atomicAdd(&cnt[dst], 1);
    int d = dst - n0;
    if ((unsigned)d < 16u) Sm[d * 68 + gl_ei[e]] = 1.0f;
  }
  __syncthreads();
  if (tid < 64) dinv[tid] = rsqrtf((float)cnt[tid]);
  __syncthreads();
  // P2: scale indicators -> coefs + self-loop
  for (int t = tid; t < 1088; t += 512) {
    int i = t / 68, s = t % 68;
    if (s < 64) {
      float di = dinv[n0 + i];
      float v = Sm[t] * dinv[s] * di;
      if (s == n0 + i) v += di * di;
      Sm[t] = v;
    }
  }
  __syncthreads();

  // P3: XA[i][w] = sum_s Sm[i][s] * x[b][w][s]  (x from L1/L2); emb cols too
  {
    int i = tid >> 5, tw = tid & 31;
    const float* Sr = Sm + i * 68;
    float o0 = 0, o1 = 0, o2 = 0, o3 = 0;
#pragma unroll 4
    for (int s4 = 0; s4 < 16; s4++) {
      float4 sv = *(const float4*)&Sr[s4 * 4];
      float4 x0 = *(const float4*)&xb[(tw)*64 + s4 * 4];
      float4 x1 = *(const float4*)&xb[(tw + 32) * 64 + s4 * 4];
      float4 x2 = *(const float4*)&xb[(tw + 64) * 64 + s4 * 4];
      float4 x3 = *(const float4*)&xb[(tw + 96) * 64 + s4 * 4];
      o0 += sv.x * x0.x + sv.y * x0.y + sv.z * x0.z + sv.w * x0.w;
      o1 += sv.x * x1.x + sv.y * x1.y + sv.z * x1.z + sv.w * x1.w;
      o2 += sv.x * x2.x + sv.y * x2.y + sv.z * x2.z + sv.w * x2.w;
      o3 += sv.x * x3.x + sv.y * x3.y + sv.z * x3.z + sv.w * x3.w;
    }
    float* Xr = XA + i * 144;
    Xr[tw] = o0; Xr[tw + 32] = o1; Xr[tw + 64] = o2; Xr[tw + 96] = o3;
  }
  if (tid < 192) {
    int i = tid / 12, j = tid % 12;
    const float* Sr = Sm + i * 68;
    float a = 0.f;
    for (int s = 0; s < 64; s++) a += Sr[s] * emb[s * 12 + j];
    XA[i * 144 + 128 + j] = a;
  }
  __syncthreads();

  int ty = tid >> 5, tx = tid & 31;   // ty = row 0..15, c0 = col
  int c0 = tx * 4;

  // P4: GEMM1: acc = XA @ Ws (K=140) + bias, relu; write back into XA after sync
  float g0 = 0, g1 = 0, g2 = 0, g3 = 0;
  {
    const float* Ar = XA + ty * 144;
#pragma unroll 4
    for (int k = 0; k < 140; k++) {
      float4 wv = *(const float4*)&Ws[k * 128 + c0];
      float a = Ar[k];
      g0 += a * wv.x; g1 += a * wv.y; g2 += a * wv.z; g3 += a * wv.w;
    }
    float4 bv = *(const float4*)&gbb[c0];
    g0 = fmaxf(g0 + bv.x, 0.f); g1 = fmaxf(g1 + bv.y, 0.f);
    g2 = fmaxf(g2 + bv.z, 0.f); g3 = fmaxf(g3 + bv.w, 0.f);
  }
  __syncthreads();   // all reads of XA/Ws done
  *(float4*)&XA[ty * 144 + c0] = make_float4(g0, g1, g2, g3);   // XA now holds hA
  // P5: stage W1 over dead Ws
  for (int t = tid; t < 10240; t += 512) {
    int k = t / 80, c = t % 80;
    Wbuf[t] = (c < HIDN) ? w1[k * HIDN + c] : 0.f;
  }
  __syncthreads();

  // P6: hm = tanh(hA @ W1 + b1)  (1280 outputs, strided)
  for (int t = tid; t < 1280; t += 512) {
    int i = t / 80, c = t % 80;
    float acc = 0.f;
    const float* Ar = XA + i * 144;
#pragma unroll 4
    for (int k = 0; k < 128; k++) acc += Ar[k] * Wbuf[k * 80 + c];
    hm[t] = tanhf(acc + (c < HIDN ? b1[c] : 0.f));
  }
  __syncthreads();
  // P7: stage W2
  {
    const float4* w24 = (const float4*)w2;
    float4* Wb4 = (float4*)Wbuf;
    for (int t = tid; t < 2464; t += 512) Wb4[t] = w24[t];
  }
  __syncthreads();

  // P8: x_rec = tanh(hm @ W2 + b2); xs = x + x_rec; recT
  {
    float a0 = 0, a1 = 0, a2 = 0, a3 = 0;
    const float* Hr = hm + ty * 80;
#pragma unroll 4
    for (int k = 0; k < HIDN; k++) {
      float4 wv = *(const float4*)&Wbuf[k * 128 + c0];
      float a = Hr[k];
      a0 += a * wv.x; a1 += a * wv.y; a2 += a * wv.z; a3 += a * wv.w;
    }
    float4 bv = *(const float4*)&b2[c0];
    float x0 = tanhf(a0 + bv.x), x1 = tanhf(a1 + bv.y);
    float x2 = tanhf(a2 + bv.z), x3 = tanhf(a3 + bv.w);
    const float* X0 = xbt + ty * 132;
    *(float4*)&xs[(size_t)(r0 + ty) * 128 + c0] =
        make_float4(X0[c0] + x0, X0[c0 + 1] + x1, X0[c0 + 2] + x2, X0[c0 + 3] + x3);
    recT[(c0 + 0) * 17 + ty] = x0; recT[(c0 + 1) * 17 + ty] = x1;
    recT[(c0 + 2) * 17 + ty] = x2; recT[(c0 + 3) * 17 + ty] = x3;
  }
  __syncthreads();
  // P9: out_rec
  float* orc = out_rec + (size_t)b * 8192 + n0;
  for (int t = tid; t < 2048; t += 512) {
    int w = t >> 4, i = t & 15;
    orc[w * 64 + i] = recT[w * 17 + i];
  }

  // ---- tail (block 1): build GAT CSR (reuses smem[0:1537] ints; regions dead) ----
  if (blockIdx.x == 1) {
    __syncthreads();
    int* ip   = (int*)smem;
    int* offs = ip;          // 65
    int* cur  = ip + 65;     // 64
    int* cntg = ip + 129;    // 64
    int* lst  = ip + 193;    // up to 1344
    if (tid < 64) cntg[tid] = 1;
    __syncthreads();
    for (int e = tid; e < E_gat; e += 512) atomicAdd(&cntg[gat_ei[BB * E_gat + e]], 1);
    __syncthreads();
    if (tid == 0) { int s = 0; for (int n = 0; n < 64; n++) { offs[n] = s; s += cntg[n]; } offs[64] = s; }
    __syncthreads();
    if (tid < 64) cur[tid] = offs[tid];
    __syncthreads();
    for (int e = tid; e < E_gat; e += 512) {
      int src = gat_ei[e], dst = gat_ei[BB * E_gat + e];
      lst[atomicAdd(&cur[dst], 1)] = src;
    }
    if (tid < 64) lst[atomicAdd(&cur[tid], 1)] = tid;
    __syncthreads();
    if (tid < 65) gat_off[tid] = offs[tid];
    int tot = offs[64];
    for (int t = tid; t < tot; t += 512) gat_list[t] = lst[t];
  }
}

// ================= K2: left/right projections =================
__global__ __launch_bounds__(256) void k_lr(const float* __restrict__ xs, const float* __restrict__ ta_w,
                                            const float* __restrict__ ta_b, float* __restrict__ leftT,
                                            float* __restrict__ rightT) {
  int wave = threadIdx.x >> 6, lane = threadIdx.x & 63;
  int idx = blockIdx.x * 4 + wave;
  int b = idx >> 7, e = idx & 127;
  int c = lane * 2;
  const float* xsb = xs + (size_t)b * 8192;
  float lx = 0, ly = 0, rx = 0, ry = 0;
#pragma unroll 4
  for (int n = 0; n < 64; n++) {
    float wl = ta_w[n * 128 + e];
    float wr = ta_w[(64 + n) * 128 + e];
    float2 xv = *(const float2*)&xsb[n * 128 + c];
    lx += wl * xv.x; ly += wl * xv.y;
    rx += wr * xv.x; ry += wr * xv.y;
  }
  float tb = ta_b[e];
  *(float2*)&leftT[((size_t)b * 128 + e) * 128 + c] = make_float2(lx + tb, ly + tb);
  *(float2*)&rightT[((size_t)b * 128 + e) * 128 + c] = make_float2(rx, ry);
}

// ================= K3: fused e-score + softmax + PV + tanh =================
__global__ __launch_bounds__(512) void k_attn(const float* __restrict__ LEFT_, const float* __restrict__ RIGHT_,
                                              const float* __restrict__ ta_a, const float* __restrict__ ta_bias,
                                              const float* __restrict__ xs, float* __restrict__ ht) {
  __shared__ float Rf[128 * 128];
  __shared__ float Lh[32 * 132];
  __shared__ float xsT[128 * 68];
  __shared__ float av2[128], av6[128], uu[32], vv[128];
  int tid = threadIdx.x;
  int b = blockIdx.x >> 2, q = blockIdx.x & 3;
  int i0 = q * 32;

  {
    const float4* R4 = (const float4*)(RIGHT_ + (size_t)b * 16384);
    float4* Rf4 = (float4*)Rf;
#pragma unroll
    for (int t = 0; t < 8; t++) Rf4[tid + t * 512] = R4[tid + t * 512];
  }
  {
    const float* Lp = LEFT_ + (size_t)b * 16384 + i0;
#pragma unroll
    for (int t = 0; t < 8; t++) {
      int idx = tid + t * 512;
      Lh[idx] = Lp[(idx >> 5) * 128 + (idx & 31)];
    }
  }
  {
    const float* xsb = xs + (size_t)b * 8192;
#pragma unroll
    for (int t = 0; t < 16; t++) {
      int idx = tid + t * 512;
      xsT[(idx & 127) * 68 + (idx >> 7)] = xsb[idx];
    }
  }
  if (tid < 128) { float a = ta_a[tid]; av2[tid] = 0.4f * a; av6[tid] = 0.6f * a; }
  __syncthreads();

  if (tid < 160) {
    float acc = 0.f;
    if (tid < 128) {
      for (int e = 0; e < 128; e++) acc += av6[e] * Rf[e * 128 + tid];
      vv[tid] = acc;
    } else {
      int i = tid - 128;
      for (int e = 0; e < 128; e++) acc += av6[e] * Lh[e * 32 + i];
      uu[i] = acc;
    }
  }
  __syncthreads();

  int tj = tid & 31, ti = tid >> 5;
  float acc[2][4];
#pragma unroll
  for (int a = 0; a < 2; a++)
#pragma unroll
    for (int j = 0; j < 4; j++) acc[a][j] = 0.f;

#pragma unroll 2
  for (int e = 0; e < 128; e++) {
    float2 L = *(const float2*)&Lh[e * 32 + ti * 2];
    float4 R = *(const float4*)&Rf[e * 128 + tj * 4];
    float ae = av2[e];
    float Ra[4] = {R.x, R.y, R.z, R.w};
    float La[2] = {L.x, L.y};
#pragma unroll
    for (int a = 0; a < 2; a++)
#pragma unroll
      for (int j = 0; j < 4; j++) {
        float t = La[a] + Ra[j];
        acc[a][j] += ae * fabsf(t);
      }
  }

  float p[2][4];
#pragma unroll
  for (int a = 0; a < 2; a++) {
    int i = i0 + ti * 2 + a;
    float uvi = uu[ti * 2 + a];
    float4 bv = *(const float4*)&ta_bias[(size_t)i * 128 + tj * 4];
    float v0 = acc[a][0] + bv.x + uvi + vv[tj * 4 + 0];
    float v1 = acc[a][1] + bv.y + uvi + vv[tj * 4 + 1];
    float v2 = acc[a][2] + bv.z + uvi + vv[tj * 4 + 2];
    float v3 = acc[a][3] + bv.w + uvi + vv[tj * 4 + 3];
    float m = fmaxf(fmaxf(v0, v1), fmaxf(v2, v3));
#pragma unroll
    for (int o = 16; o > 0; o >>= 1) m = fmaxf(m, __shfl_xor(m, o));
    float e0 = __expf(v0 - m), e1 = __expf(v1 - m), e2 = __expf(v2 - m), e3 = __expf(v3 - m);
    float s = e0 + e1 + e2 + e3;
#pragma unroll
    for (int o = 16; o > 0; o >>= 1) s += __shfl_xor(s, o);
    float inv = 1.f / s;
    p[a][0] = e0 * inv; p[a][1] = e1 * inv; p[a][2] = e2 * inv; p[a][3] = e3 * inv;
  }
  __syncthreads();
  float* P = Lh;
  *(float4*)&P[(ti * 2 + 0) * 132 + tj * 4] = make_float4(p[0][0], p[0][1], p[0][2], p[0][3]);
  *(float4*)&P[(ti * 2 + 1) * 132 + tj * 4] = make_float4(p[1][0], p[1][1], p[1][2], p[1][3]);
  __syncthreads();

  int tn = tid & 15, i2 = tid >> 4;
  float o0 = 0, o1 = 0, o2 = 0, o3 = 0;
  const float* Prow = P + i2 * 132;
#pragma unroll 4
  for (int j = 0; j < 128; j++) {
    float4 xv = *(const float4*)&xsT[j * 68 + tn * 4];
    float pv = Prow[j];
    o0 += pv * xv.x; o1 += pv * xv.y; o2 += pv * xv.z; o3 += pv * xv.w;
  }
  float* hto = ht + (size_t)b * 8192 + (size_t)(i0 + i2) * 64 + tn * 4;
  *(float4*)hto = make_float4(tanhf(o0), tanhf(o1), tanhf(o2), tanhf(o3));
}

// ================= K4: fused GAT per batch: GEMM (LDS W) + edge-softmax + FC =================
__global__ __launch_bounds__(1024) void k_gat(const float* __restrict__ ht, const float* __restrict__ gw,
                                              const float* __restrict__ asrc, const float* __restrict__ adst,
                                              const float* __restrict__ gb, const float* __restrict__ fcw,
                                              const float* __restrict__ fcb,
                                              const int* __restrict__ off, const int* __restrict__ list,
                                              float* __restrict__ outp) {
  __shared__ float Ws[128 * 128];   // 64 KB
  __shared__ float AsT[64 * 132];   // 33 KB
  __shared__ float H2[64 * 132];    // 33 KB
  __shared__ float ss_s[64], sd_s[64];
  __shared__ int offs_s[65];
  __shared__ int list_s[1408];
  int tid = threadIdx.x, b = blockIdx.x;
  {
    const float4* W4 = (const float4*)gw;
    float4* Ws4 = (float4*)Ws;
    for (int t = tid; t < 4096; t += 1024) Ws4[t] = W4[t];
  }
  const float* hb = ht + (size_t)b * 8192;
  for (int t = tid; t < 8192; t += 1024) {
    int k = t >> 6, n = t & 63;
    AsT[n * 132 + k] = hb[t];
  }
  if (tid < 65) offs_s[tid] = off[tid];
  __syncthreads();
  int totE = offs_s[64];
  for (int t = tid; t < totE; t += 1024) list_s[t] = list[t];

  int tx = tid & 31, ty = tid >> 5;     // ty 0..31 -> 2 rows each
  int c0 = tx * 4, row0 = ty * 2;
  float a00 = 0, a01 = 0, a02 = 0, a03 = 0, a10 = 0, a11 = 0, a12 = 0, a13 = 0;
  const float* A0 = AsT + row0 * 132;
  const float* A1 = A0 + 132;
#pragma unroll 4
  for (int k = 0; k < 128; k++) {
    float4 wv = *(const float4*)&Ws[k * 128 + c0];
    float a0 = A0[k], a1 = A1[k];
    a00 += a0 * wv.x; a01 += a0 * wv.y; a02 += a0 * wv.z; a03 += a0 * wv.w;
    a10 += a1 * wv.x; a11 += a1 * wv.y; a12 += a1 * wv.z; a13 += a1 * wv.w;
  }
  float4 as4 = *(const float4*)&asrc[c0];
  float4 ad4 = *(const float4*)&adst[c0];
  *(float4*)&H2[row0 * 132 + c0] = make_float4(a00, a01, a02, a03);
  *(float4*)&H2[(row0 + 1) * 132 + c0] = make_float4(a10, a11, a12, a13);
  float ss0 = a00 * as4.x + a01 * as4.y + a02 * as4.z + a03 * as4.w;
  float sd0 = a00 * ad4.x + a01 * ad4.y + a02 * ad4.z + a03 * ad4.w;
  float ss1 = a10 * as4.x + a11 * as4.y + a12 * as4.z + a13 * as4.w;
  float sd1 = a10 * ad4.x + a11 * ad4.y + a12 * ad4.z + a13 * ad4.w;
#pragma unroll
  for (int m = 16; m > 0; m >>= 1) {
    ss0 += __shfl_xor(ss0, m); sd0 += __shfl_xor(sd0, m);
    ss1 += __shfl_xor(ss1, m); sd1 += __shfl_xor(sd1, m);
  }
  if (tx == 0) {
    ss_s[row0] = ss0; sd_s[row0] = sd0;
    ss_s[row0 + 1] = ss1; sd_s[row0 + 1] = sd1;
  }
  __syncthreads();

  // edge softmax + aggregate: thread = 1 row x 8 cols
  int row = tid >> 4, tc = tid & 15;
  int cb = tc * 8;
  int e0 = offs_s[row], e1 = offs_s[row + 1];
  float sdv = sd_s[row];
  float mx = -1e30f;
  for (int e = e0; e < e1; e++) {
    float t = ss_s[list_s[e]] + sdv;
    t = fmaxf(t, 0.2f * t);
    mx = fmaxf(mx, t);
  }
  float den = 0.f;
  float o[8];
#pragma unroll
  for (int j = 0; j < 8; j++) o[j] = 0.f;
  for (int e = e0; e < e1; e++) {
    int s = list_s[e];
    float t = ss_s[s] + sdv;
    t = fmaxf(t, 0.2f * t);
    float w = __expf(t - mx);
    den += w;
    const float* hp = &H2[s * 132 + cb];
    float4 h0 = *(const float4*)hp;
    float4 h1 = *(const float4*)(hp + 4);
    o[0] += w * h0.x; o[1] += w * h0.y; o[2] += w * h0.z; o[3] += w * h0.w;
    o[4] += w * h1.x; o[5] += w * h1.y; o[6] += w * h1.z; o[7] += w * h1.w;
  }
  float inv = 1.f / den;
  float xp = 0.f;
#pragma unroll
  for (int j = 0; j < 8; j++) xp += (o[j] * inv + gb[cb + j]) * fcw[cb + j];
#pragma unroll
  for (int m = 8; m > 0; m >>= 1) xp += __shfl_xor(xp, m);
  if (tc == 0) outp[b * 64 + row] = tanhf(xp + fcb[0]);
}

extern "C" void kernel_launch(void* const* d_in, const int* in_sizes, int n_in,
                              void* d_out, int out_size, void* d_ws, size_t ws_size,
                              hipStream_t stream) {
  (void)n_in; (void)out_size; (void)ws_size;
  const float* x        = (const float*)d_in[0];
  const float* gl_embed = (const float*)d_in[7];
  const float* gcn_w    = (const float*)d_in[8];
  const float* gcn_b    = (const float*)d_in[9];
  const float* mlp_w1   = (const float*)d_in[10];
  const float* mlp_b1   = (const float*)d_in[11];
  const float* mlp_w2   = (const float*)d_in[12];
  const float* mlp_b2   = (const float*)d_in[13];
  const float* ta_w     = (const float*)d_in[14];
  const float* ta_b     = (const float*)d_in[15];
  const float* ta_a     = (const float*)d_in[16];
  const float* ta_bias  = (const float*)d_in[17];
  const float* gat_w    = (const float*)d_in[18];
  const float* gat_asrc = (const float*)d_in[19];
  const float* gat_adst = (const float*)d_in[20];
  const float* gat_b    = (const float*)d_in[21];
  const float* fc_w     = (const float*)d_in[22];
  const float* fc_b     = (const float*)d_in[23];
  const int*   gat_ei   = (const int*)d_in[24];
  const int*   gl_ei    = (const int*)d_in[25];

  int E_gat = in_sizes[24] / (2 * BB);  // 1280
  int E_gl  = in_sizes[25] / (2 * BB);  // 1638

  float* ws = (float*)d_ws;
  float* XS    = ws + 0;        // 524288
  float* LEFT  = ws + 524288;   // 1048576
  float* RIGHT = ws + 1572864;  // 1048576
  float* HT    = ws + 2621440;  // 524288
  int*   IP    = (int*)(ws + 3145728);
  int* GATOFF  = IP;            // 72
  int* GATLIST = IP + 72;       // 2048

  float* out_rec = (float*)d_out;
  float* out_pre = (float*)d_out + 524288;

  k_front<<<256, 512, 0, stream>>>(x, gl_embed, gcn_w, gcn_b, mlp_w1, mlp_b1, mlp_w2, mlp_b2,
                                   gl_ei, E_gl, gat_ei, E_gat, XS, out_rec, GATOFF, GATLIST);
  k_lr<<<2048, 256, 0, stream>>>(XS, ta_w, ta_b, LEFT, RIGHT);
  k_attn<<<256, 512, 0, stream>>>(LEFT, RIGHT, ta_a, ta_bias, XS, HT);
  k_gat<<<64, 1024, 0, stream>>>(HT, gat_w, gat_asrc, gat_adst, gat_b, fc_w, fc_b,
                                 GATOFF, GATLIST, out_pre);
}